// Round 18
// baseline (231.497 us; speedup 1.0000x reference)
//
#include <hip/hip_runtime.h>
#include <hip/hip_bf16.h>

#define N_ 1024
#define C_ 768
#define H_ 12

typedef unsigned short u16;
typedef __attribute__((ext_vector_type(8))) short bf16x8;
typedef __attribute__((ext_vector_type(4))) float f32x4;
typedef __attribute__((ext_vector_type(16))) float f32x16;

#define MFMA16(a, b, c) __builtin_amdgcn_mfma_f32_16x16x32_bf16(a, b, c, 0, 0, 0)
#define MFMA32(a, b, c) __builtin_amdgcn_mfma_f32_32x32x16_bf16(a, b, c, 0, 0, 0)

#define GLDS16(gp, lp) __builtin_amdgcn_global_load_lds(                     \
    (const __attribute__((address_space(1))) void*)(gp),                     \
    (__attribute__((address_space(3))) void*)(lp), 16, 0, 0)

// fp32 -> bf16 bits, round-to-nearest-even
__device__ __forceinline__ u16 f2bu(float x) {
    unsigned u = __float_as_uint(x);
    unsigned r = (u + 0x7fffu + ((u >> 16) & 1u)) >> 16;
    return (u16)r;
}

// pack two fp32 -> u32 of 2x bf16 (lo = a, hi = b)
__device__ __forceinline__ unsigned cvtpk(float a, float b) {
    unsigned d;
    asm("v_cvt_pk_bf16_f32 %0, %1, %2" : "=v"(d) : "v"(a), "v"(b));
    return d;
}

// ---------------------------------------------------------------------------
// Fused preprocessing (round-17 proven): transpose+cvt weights, cvt x1/x2.
// ---------------------------------------------------------------------------
__global__ __launch_bounds__(256) void prep(
    const float* __restrict__ x1, const float* __restrict__ x2,
    const float* __restrict__ qkv_w, const float* __restrict__ proj_w,
    u16* __restrict__ d1, u16* __restrict__ d2,
    u16* __restrict__ wqkvT, u16* __restrict__ wprojT)
{
    const int bid = blockIdx.x;
    if (bid < 2304) {
        __shared__ float t[32][33];
        const int txi = bid % 96, ty = bid / 96;
        const bool isq = txi < 72;
        const float* W = isq ? qkv_w : proj_w;
        u16* WT = isq ? wqkvT : wprojT;
        const int CC = isq ? 2304 : 768;
        const int c0 = (isq ? txi : txi - 72) * 32;
        const int r0 = ty * 32;
        const int tx = threadIdx.x & 31, tyy = threadIdx.x >> 5;
#pragma unroll
        for (int i = 0; i < 4; ++i) {
            int r = tyy + i * 8;
            t[r][tx] = W[(size_t)(r0 + r) * CC + c0 + tx];
        }
        __syncthreads();
#pragma unroll
        for (int i = 0; i < 4; ++i) {
            int c = tyy + i * 8;
            WT[(size_t)(c0 + c) * 768 + r0 + tx] = f2bu(t[tx][c]);
        }
    } else {
        const size_t G = 786432;
        for (size_t i = (size_t)(bid - 2304) * 256 + threadIdx.x; i < 2 * G;
             i += (size_t)1536 * 256) {
            const float* src = (i < G) ? x1 : x2;
            u16* dst = (i < G) ? d1 : d2;
            size_t g = (i < G) ? i : i - G;
            float4 f0 = ((const float4*)src)[g * 2];
            float4 f1 = ((const float4*)src)[g * 2 + 1];
            ushort4 lo, hi;
            lo.x = f2bu(f0.x); lo.y = f2bu(f0.y); lo.z = f2bu(f0.z); lo.w = f2bu(f0.w);
            hi.x = f2bu(f1.x); hi.y = f2bu(f1.y); hi.z = f2bu(f1.z); hi.w = f2bu(f1.w);
            ((ushort4*)dst)[g * 2] = lo;
            ((ushort4*)dst)[g * 2 + 1] = hi;
        }
    }
}

// ---------------------------------------------------------------------------
// QKV GEMM — 8-phase counted-vmcnt schedule (T3+T4), 256x256 tile.
// Grid 480 = 8 xcd x 4 row-panels x 15 col-tiles (sections align: 768=3*256).
// 512 thr = 8 waves (2M x 4N), per-wave 128x64, acc[4][2] f32x16.
// LDS 128KB: As/Bs [dbuf 2][half 2][128x64]. Iter = 2 K-tiles = 8 phases;
// phase p: {stage 1 half-tile; (p==0/4: vmcnt(2)+ready-barrier); 6 ds_read;
//           setprio(1) 8xMFMA32 setprio(0); fence; barrier}.
// HAZARD AUDIT: stage@p0-3 -> tile 2i+1 (dbuf1) whose halves were last read
// in phases 4-7 of iter i-1, all waves past the phase-7 barrier. stage@p4-7
// -> tile 2i+2 (dbuf0), last read phases 0-3, past phase-3 barrier. vmcnt(2)
// at p0/p4 leaves only the 2 just-issued loads outstanding -> current tile's
// 8 loads (issued 4..7 phases earlier) have landed; barrier makes it global.
// Steady state never drains vmcnt to 0 (only iter-5 phase-4).
// Accumulation order identical to round-16 (bit-identical results).
// ---------------------------------------------------------------------------
__global__ __launch_bounds__(512) void qkv_gemm(
    const u16* __restrict__ A1, const u16* __restrict__ A2,
    const u16* __restrict__ BT, u16* __restrict__ qd,
    u16* __restrict__ k1d, u16* __restrict__ k2d,
    u16* __restrict__ vt1d, u16* __restrict__ vt2d)
{
    __shared__ u16 As[2][2][8192];   // [dbuf][half][128*64] = 64 KB
    __shared__ u16 Bs[2][2][8192];   // 64 KB
    const int tid = threadIdx.x;     // 0..511
    const int w = tid >> 6, lane = tid & 63;
    const int c31 = lane & 31, h = lane >> 5;
    const int wm = w >> 2, wn = w & 3;
    const int id = blockIdx.x;       // 0..479
    const int xcd = id & 7, j = id >> 3;   // j 0..59
    const int by = xcd * 4 + j / 15;       // 0..31
    const int bx = j % 15;
    const bool first = bx < 9;
    const u16* Ain = first ? A1 : A2;
    const int row0 = by * 256;
    const int bcol0 = first ? bx * 256 : 768 + (bx - 9) * 256;

    f32x16 acc[4][2];
#pragma unroll
    for (int i = 0; i < 4; ++i)
#pragma unroll
        for (int jj = 0; jj < 2; ++jj)
#pragma unroll
            for (int e = 0; e < 16; ++e) acc[i][jj][e] = 0.f;

    // staging geometry: half-tile = 128 rows x 64 k = 16KB = 512thr x 2 x 16B
    // thread covers rows r0t and 64+r0t; source chunk = (tid&7)^(r0t&7)
    const int r0t = tid >> 3;                       // 0..63
    const int csrc = ((tid & 7) ^ (r0t & 7)) * 8;   // element offset
    const u16* srcA = Ain + (size_t)(row0 + r0t) * 768 + csrc;
    const u16* srcB = BT + (size_t)(bcol0 + r0t) * 768 + csrc;
    char* dstA = (char*)As + w * 1024;   // wave-uniform base; HW adds lane*16
    char* dstB = (char*)Bs + w * 1024;

    // part: 0=A half0, 1=A half1, 2=B half0, 3=B half1
    auto stage = [&](int ts, int part) {
        const int d = ts & 1, hf = part & 1;
        const int lb = (d * 2 + hf) << 14;          // 16KB per [dbuf][half]
        const int go = hf * 98304 + ts * 64;        // hf*128*768 + tile k-off
        if (part < 2) {
            GLDS16(srcA + go,         dstA + lb);
            GLDS16(srcA + go + 49152, dstA + lb + 8192);   // rows 64..127
        } else {
            GLDS16(srcB + go,         dstB + lb);
            GLDS16(srcB + go + 49152, dstB + lb + 8192);
        }
    };

    // prologue: stage tile 0 fully (8 loads/thread)
    stage(0, 0); stage(0, 1); stage(0, 2); stage(0, 3);

    for (int it = 0; it < 6; ++it) {
#pragma unroll
        for (int p = 0; p < 8; ++p) {
            const int d = p >> 2;                  // dbuf of current tile
            const int kh = p & 3;                  // K=16 slice within BK=64
            const int ts = 2 * it + 1 + d;         // staged tile this phase
            if (ts < 12) stage(ts, p & 3);
            if (p == 0) {
                asm volatile("s_waitcnt vmcnt(2)" ::: "memory");
                __builtin_amdgcn_s_barrier();
            } else if (p == 4) {
                if (it < 5) asm volatile("s_waitcnt vmcnt(2)" ::: "memory");
                else        asm volatile("s_waitcnt vmcnt(0)" ::: "memory");
                __builtin_amdgcn_s_barrier();
            }
            const char* ab = (const char*)As + ((d * 2 + wm) << 14);
            const char* bb = (const char*)Bs + ((d * 2 + (wn >> 1)) << 14);
            bf16x8 af[4], bfr[2];
#pragma unroll
            for (int mt = 0; mt < 4; ++mt) {
                int ar = mt * 32 + c31;
                af[mt] = *(const bf16x8*)(ab + ar * 128 + (((kh * 2 + h) ^ (ar & 7)) * 16));
            }
#pragma unroll
            for (int nt = 0; nt < 2; ++nt) {
                int br = (wn & 1) * 64 + nt * 32 + c31;
                bfr[nt] = *(const bf16x8*)(bb + br * 128 + (((kh * 2 + h) ^ (br & 7)) * 16));
            }
            __builtin_amdgcn_s_setprio(1);
#pragma unroll
            for (int mt = 0; mt < 4; ++mt)
#pragma unroll
                for (int nt = 0; nt < 2; ++nt)
                    acc[mt][nt] = MFMA32(af[mt], bfr[nt], acc[mt][nt]);
            __builtin_amdgcn_s_setprio(0);
            asm volatile("" ::: "memory");
            __builtin_amdgcn_s_barrier();
        }
    }

    u16* kd  = first ? k1d : k2d;
    u16* vtd = first ? vt1d : vt2d;
#pragma unroll
    for (int mt = 0; mt < 4; ++mt)
#pragma unroll
        for (int nt = 0; nt < 2; ++nt) {
            const int col = bcol0 + wn * 64 + nt * 32 + c31;
            const int sec = col / C_;            // 0=q 1=k 2=v (uniform/nt)
            const int hh = (col % C_) >> 6;
            const int dd = col & 63;
            const float scl = (sec == 0) ? 0.180336877f : 1.0f;
#pragma unroll
            for (int r = 0; r < 16; ++r) {
                int row = row0 + wm * 128 + mt * 32 + (r & 3) + 8 * (r >> 2) + 4 * h;
                int b = row >> 10, n = row & 1023;
                u16 val = f2bu(acc[mt][nt][r] * scl);
                size_t bh = (size_t)(b * H_ + hh);
                if (sec == 0)      qd[(bh * N_ + n) * 64 + dd] = val;
                else if (sec == 1) kd[(bh * N_ + n) * 64 + dd] = val;
                else {
                    int nprm = (n & ~63) | (((n & 15) << 2) | ((n >> 4) & 3));
                    vtd[(bh * 64 + dd) * N_ + nprm] = val;
                }
            }
        }
}

// ---------------------------------------------------------------------------
// Proj GEMM (round-16/17 proven): 512-thr, BK=64 2-phase, XCD swizzle.
// ---------------------------------------------------------------------------
__global__ __launch_bounds__(512) void proj_gemm(
    const u16* __restrict__ A1, const u16* __restrict__ A2,
    const u16* __restrict__ BT, const float* __restrict__ bias,
    float* __restrict__ out)
{
    __shared__ u16 As[2][128 * 64];
    __shared__ u16 Bs[2][128 * 64];
    const int tid = threadIdx.x;
    const int w = tid >> 6, lane = tid & 63;
    const int c31 = lane & 31, h = lane >> 5;
    const int wm = w >> 2, wn = w & 3;
    const int id = blockIdx.x;             // 0..767
    const int xcd = id & 7, j = id >> 3;   // j 0..95
    const int byg = xcd * 16 + j / 6;      // 0..127
    const int sel = byg >> 6;
    const u16* A = sel ? A2 : A1;
    float* op = out + (size_t)sel * 8192 * C_;
    const int row0 = (byg & 63) * 128;
    const int nc0 = (j % 6) * 128;

    f32x16 acc[2];
#pragma unroll
    for (int i = 0; i < 2; ++i)
#pragma unroll
        for (int e = 0; e < 16; ++e) acc[i][e] = 0.f;

    const int srow = tid >> 3;
    const int sch = ((tid & 7) ^ (srow & 7)) * 8;
    int aoff[2], boff[2];
#pragma unroll
    for (int i = 0; i < 2; ++i) {
        int row = i * 64 + srow;
        aoff[i] = (row0 + row) * C_ + sch;
        boff[i] = (nc0 + row) * C_ + sch;
    }
    char* adst0 = (char*)&As[0][0] + w * 1024;
    char* bdst0 = (char*)&Bs[0][0] + w * 1024;
    auto stage = [&](int buf, int k0) {
#pragma unroll
        for (int i = 0; i < 2; ++i) {
            GLDS16(A + aoff[i] + k0, adst0 + buf * 16384 + i * 8192);
            GLDS16(BT + boff[i] + k0, bdst0 + buf * 16384 + i * 8192);
        }
    };

    const int ra0 = wm * 64 + c31, ra1 = ra0 + 32;
    const int rb0 = wn * 32 + c31;

    stage(0, 0);
    for (int kt = 0; kt < 12; ++kt) {
        const int buf = kt & 1;
        if (kt < 11) {
            stage(buf ^ 1, (kt + 1) * 64);
            asm volatile("s_waitcnt vmcnt(4)" ::: "memory");
        } else {
            asm volatile("s_waitcnt vmcnt(0)" ::: "memory");
        }
        __builtin_amdgcn_s_barrier();
        const char* abase = (const char*)&As[0][0] + buf * 16384;
        const char* bbase = (const char*)&Bs[0][0] + buf * 16384;
#pragma unroll
        for (int kh = 0; kh < 4; ++kh) {
            bf16x8 a0 = *(const bf16x8*)(abase + ra0 * 128 + (((2 * kh + h) ^ (ra0 & 7)) * 16));
            bf16x8 a1 = *(const bf16x8*)(abase + ra1 * 128 + (((2 * kh + h) ^ (ra1 & 7)) * 16));
            bf16x8 b0 = *(const bf16x8*)(bbase + rb0 * 128 + (((2 * kh + h) ^ (rb0 & 7)) * 16));
            acc[0] = MFMA32(a0, b0, acc[0]);
            acc[1] = MFMA32(a1, b0, acc[1]);
        }
        asm volatile("" ::: "memory");
        __builtin_amdgcn_s_barrier();
    }

    const int col = nc0 + wn * 32 + c31;
#pragma unroll
    for (int mt = 0; mt < 2; ++mt)
#pragma unroll
        for (int r = 0; r < 16; ++r) {
            int row = row0 + wm * 64 + mt * 32 + (r & 3) + 8 * (r >> 2) + 4 * h;
            op[(size_t)row * C_ + col] = acc[mt][r] + bias[col];
        }
}

// ---------------------------------------------------------------------------
// MFMA flash attention (round-17 proven), softmax-lite, both branches.
// ---------------------------------------------------------------------------
__global__ __launch_bounds__(256) void attn_mfma(
    const u16* __restrict__ Q,
    const u16* __restrict__ K1, const u16* __restrict__ VT1,
    const u16* __restrict__ K2, const u16* __restrict__ VT2,
    u16* __restrict__ O1, u16* __restrict__ O2)
{
    __shared__ u16 Ks[2][64 * 64];
    __shared__ u16 Vs[2][64 * 64];
    __shared__ u16 Ps[4][32 * 72];
    const int tid = threadIdx.x;
    const int w = tid >> 6, lane = tid & 63;
    const int g = lane >> 4, ln = lane & 15;
    const int id = blockIdx.x;
    const int xcd = id & 7, j = id >> 3;
    const int unit = j >> 3;
    const int qb = j & 7;
    const int br = unit >= 12;
    const int bh = xcd * 12 + (br ? unit - 12 : unit);
    const int qw = qb * 128 + w * 32;
    const size_t hb = (size_t)bh * N_ * 64;

    const u16* Kb = (br ? K2 : K1) + hb;
    const u16* Vb = (br ? VT2 : VT1) + hb;
    const u16* Qb = Q + hb;
    u16* O        = br ? O2 : O1;

    bf16x8 qf[2][2];
#pragma unroll
    for (int mt = 0; mt < 2; ++mt)
#pragma unroll
        for (int s = 0; s < 2; ++s)
            qf[mt][s] = *(const bf16x8*)(Qb + (size_t)(qw + mt * 16 + ln) * 64 + s * 32 + g * 8);

    f32x4 o[2][4];
    float lsum[2][4];
#pragma unroll
    for (int mt = 0; mt < 2; ++mt) {
#pragma unroll
        for (int t = 0; t < 4; ++t) o[mt][t] = (f32x4){0.f, 0.f, 0.f, 0.f};
#pragma unroll
        for (int r = 0; r < 4; ++r) lsum[mt][r] = 0.f;
    }

    auto stage = [&](int buf, int key0) {
#pragma unroll
        for (int i = 0; i < 2; ++i) {
            int L = (i * 256 + tid) * 16;
            int row = L >> 7;
            int sw = (((L >> 4) & 7) ^ (row & 7)) * 8;
            GLDS16(Kb + (size_t)(key0 + row) * 64 + sw,
                   (char*)&Ks[buf][0] + i * 4096 + w * 1024);
            GLDS16(Vb + (size_t)row * N_ + key0 + sw,
                   (char*)&Vs[buf][0] + i * 4096 + w * 1024);
        }
    };

    u16* pw = &Ps[w][0];
    const int r7 = ln & 7;

    stage(0, 0);
    __syncthreads();
    for (int kt = 0; kt < 16; ++kt) {
        const int buf = kt & 1;
        if (kt < 15) stage(buf ^ 1, (kt + 1) * 64);
        const char* kbase = (const char*)&Ks[buf][0];
        f32x4 st[2][4];
        __builtin_amdgcn_s_setprio(1);
#pragma unroll
        for (int nt = 0; nt < 4; ++nt) {
            const char* krow = kbase + (nt * 16 + ln) * 128;
            bf16x8 kf0 = *(const bf16x8*)(krow + ((g ^ r7) * 16));
            bf16x8 kf1 = *(const bf16x8*)(krow + (((g + 4) ^ r7) * 16));
#pragma unroll
            for (int mt = 0; mt < 2; ++mt) {
                f32x4 z = (f32x4){0.f, 0.f, 0.f, 0.f};
                z = MFMA16(qf[mt][0], kf0, z);
                z = MFMA16(qf[mt][1], kf1, z);
                st[mt][nt] = z;
            }
        }
        __builtin_amdgcn_s_setprio(0);
#pragma unroll
        for (int mt = 0; mt < 2; ++mt)
#pragma unroll
            for (int r = 0; r < 4; ++r) {
                float p0 = __builtin_amdgcn_exp2f(st[mt][0][r]);
                float p1 = __builtin_amdgcn_exp2f(st[mt][1][r]);
                float p2 = __builtin_amdgcn_exp2f(st[mt][2][r]);
                float p3 = __builtin_amdgcn_exp2f(st[mt][3][r]);
                lsum[mt][r] += (p0 + p1) + (p2 + p3);
                uint2 pk;
                pk.x = cvtpk(p0, p1);
                pk.y = cvtpk(p2, p3);
                int prow = mt * 16 + g * 4 + r;
                *(uint2*)((char*)pw + prow * 144 + ln * 8) = pk;
            }
        const char* vbase = (const char*)&Vs[buf][0];
        __builtin_amdgcn_s_setprio(1);
#pragma unroll
        for (int s = 0; s < 2; ++s) {
            bf16x8 pa[2];
            pa[0] = *(const bf16x8*)((const char*)pw + (0 + ln) * 144 + s * 64 + g * 16);
            pa[1] = *(const bf16x8*)((const char*)pw + (16 + ln) * 144 + s * 64 + g * 16);
#pragma unroll
            for (int t = 0; t < 4; ++t) {
                bf16x8 vf = *(const bf16x8*)(vbase + (t * 16 + ln) * 128 + (((s * 4 + g) ^ r7) * 16));
#pragma unroll
                for (int mt = 0; mt < 2; ++mt) o[mt][t] = MFMA16(pa[mt], vf, o[mt][t]);
            }
        }
        __builtin_amdgcn_s_setprio(0);
        __syncthreads();
    }
    const int b = bh / H_, h = bh % H_;
#pragma unroll
    for (int mt = 0; mt < 2; ++mt)
#pragma unroll
        for (int r = 0; r < 4; ++r) {
            float ls = lsum[mt][r];
#pragma unroll
            for (int off = 8; off; off >>= 1) ls += __shfl_xor(ls, off);
            float inv = 1.f / ls;
            int n = qw + mt * 16 + g * 4 + r;
            u16* orow = O + ((size_t)(b * N_) + n) * C_ + h * 64 + ln;
#pragma unroll
            for (int t = 0; t < 4; ++t)
                orow[t * 16] = f2bu(o[mt][t][r] * inv);
        }
}

extern "C" void kernel_launch(void* const* d_in, const int* in_sizes, int n_in,
                              void* d_out, int out_size, void* d_ws, size_t ws_size,
                              hipStream_t stream) {
    const float* x1     = (const float*)d_in[0];
    const float* x2     = (const float*)d_in[1];
    const float* qkv_w  = (const float*)d_in[2];
    const float* proj_w = (const float*)d_in[3];
    const float* proj_b = (const float*)d_in[4];
    float* out = (float*)d_out;

    // ws layout (u16), 80.2 MB (proven). Alias plan (merge-safe):
    //   x1c/x2c in slotA/slotB are qkv INPUTS only (outputs never alias them);
    //   k2 lives in d_out's out2 region. After qkv both slots are dead ->
    //   attn writes o1p=slotB, o2p=slotA. proj (merged) reads o1p/o2p (ws),
    //   writes out: out2 clobbers dead k2buf; out1 clobbers nothing live.
    u16* ws = (u16*)d_ws;
    const size_t SZ = (size_t)8 * H_ * N_ * 64;  // 6291456 (= 8192*768)
    u16* wqkvT  = ws;
    u16* wprojT = wqkvT + (size_t)2304 * 768;
    u16* q      = wprojT + (size_t)768 * 768;
    u16* k1     = q + SZ;
    u16* vT1    = k1 + SZ;
    u16* slotA  = vT1 + SZ;   // x1c during qkv; o2p afterwards
    u16* vT2    = slotA + SZ;
    u16* slotB  = vT2 + SZ;   // x2c during qkv; o1p afterwards
    u16* x1c = slotA, *o2p = slotA;
    u16* x2c = slotB, *o1p = slotB;
    u16* k2buf = (u16*)(out + SZ);   // scratch inside out-branch-2 region

    prep<<<3840, 256, 0, stream>>>(x1, x2, qkv_w, proj_w, x1c, x2c, wqkvT, wprojT);
    qkv_gemm<<<480, 512, 0, stream>>>(x1c, x2c, wqkvT, q, k1, k2buf, vT1, vT2);
    attn_mfma<<<1536, 256, 0, stream>>>(q, k1, vT1, k2buf, vT2, o1p, o2p);
    proj_gemm<<<768, 512, 0, stream>>>(o1p, o2p, wprojT, proj_b, out);
}

// Round 19
// 206.330 us; speedup vs baseline: 1.1220x; 1.1220x over previous
//
#include <hip/hip_runtime.h>
#include <hip/hip_bf16.h>

#define N_ 1024
#define C_ 768
#define H_ 12

typedef unsigned short u16;
typedef __attribute__((ext_vector_type(8))) short bf16x8;
typedef __attribute__((ext_vector_type(4))) float f32x4;
typedef __attribute__((ext_vector_type(16))) float f32x16;

#define MFMA16(a, b, c) __builtin_amdgcn_mfma_f32_16x16x32_bf16(a, b, c, 0, 0, 0)
#define MFMA32(a, b, c) __builtin_amdgcn_mfma_f32_32x32x16_bf16(a, b, c, 0, 0, 0)

#define GLDS16(gp, lp) __builtin_amdgcn_global_load_lds(                     \
    (const __attribute__((address_space(1))) void*)(gp),                     \
    (__attribute__((address_space(3))) void*)(lp), 16, 0, 0)

// fp32 -> bf16 bits, round-to-nearest-even
__device__ __forceinline__ u16 f2bu(float x) {
    unsigned u = __float_as_uint(x);
    unsigned r = (u + 0x7fffu + ((u >> 16) & 1u)) >> 16;
    return (u16)r;
}

// pack two fp32 -> u32 of 2x bf16 (lo = a, hi = b)
__device__ __forceinline__ unsigned cvtpk(float a, float b) {
    unsigned d;
    asm("v_cvt_pk_bf16_f32 %0, %1, %2" : "=v"(d) : "v"(a), "v"(b));
    return d;
}

// ---------------------------------------------------------------------------
// Convert x (fp32) -> bf16, both tensors in one launch.
// ---------------------------------------------------------------------------
__global__ __launch_bounds__(256) void cvt_x(
    const float* __restrict__ x1, const float* __restrict__ x2,
    u16* __restrict__ d1, u16* __restrict__ d2)
{
    const size_t G = 786432;  // groups of 8 floats per tensor
    for (size_t i = (size_t)blockIdx.x * 256 + threadIdx.x; i < 2 * G;
         i += (size_t)gridDim.x * 256) {
        const float* src = (i < G) ? x1 : x2;
        u16* dst = (i < G) ? d1 : d2;
        size_t g = (i < G) ? i : i - G;
        float4 f0 = ((const float4*)src)[g * 2];
        float4 f1 = ((const float4*)src)[g * 2 + 1];
        ushort4 lo, hi;
        lo.x = f2bu(f0.x); lo.y = f2bu(f0.y); lo.z = f2bu(f0.z); lo.w = f2bu(f0.w);
        hi.x = f2bu(f1.x); hi.y = f2bu(f1.y); hi.z = f2bu(f1.z); hi.w = f2bu(f1.w);
        ((ushort4*)dst)[g * 2] = lo;
        ((ushort4*)dst)[g * 2 + 1] = hi;
    }
}

// ---------------------------------------------------------------------------
// Convert + transpose fp32 W[R][CC] -> bf16 WT[CC][R]
// ---------------------------------------------------------------------------
__global__ __launch_bounds__(256) void tr_cvt(
    const float* __restrict__ W, u16* __restrict__ WT, int R, int CC)
{
    __shared__ float t[32][33];
    const int tx = threadIdx.x & 31, ty = threadIdx.x >> 5;
    const int c0 = blockIdx.x * 32, r0 = blockIdx.y * 32;
#pragma unroll
    for (int i = 0; i < 4; ++i) {
        int r = ty + i * 8;
        t[r][tx] = W[(size_t)(r0 + r) * CC + c0 + tx];
    }
    __syncthreads();
#pragma unroll
    for (int i = 0; i < 4; ++i) {
        int c = ty + i * 8;
        WT[(size_t)(c0 + c) * R + r0 + tx] = f2bu(t[tx][c]);
    }
}

// ---------------------------------------------------------------------------
// QKV GEMM, both inputs in one dispatch, flat grid 1920 with XCD swizzle.
// 512-thread blocks (8 waves, wave grid 2x4, per-wave 64x32 output, acc=32
// regs) on 128x128 tile / BK=64 / 64KB dbuf LDS -> 16 waves/CU resident.
// Cross-barrier prefetch: issue stage(k+1) -> vmcnt(4) [wait stage k only]
// -> s_barrier -> compute(k) -> fence + s_barrier.
// Staging rows 128B (8 chunks), chunk swizzle ^(row&7).
// 32x32 frag maps (HW-verified): A row=lane&31, k=(lane>>5)*8+e;
// C/D col=lane&31, row=(r&3)+8*(r>>2)+4*(lane>>5).
// ---------------------------------------------------------------------------
__global__ __launch_bounds__(512) void qkv_gemm(
    const u16* __restrict__ A1, const u16* __restrict__ A2,
    const u16* __restrict__ BT, u16* __restrict__ qd,
    u16* __restrict__ k1d, u16* __restrict__ k2d,
    u16* __restrict__ vt1d, u16* __restrict__ vt2d)
{
    __shared__ u16 As[2][128 * 64];   // 16KB x2
    __shared__ u16 Bs[2][128 * 64];   // 16KB x2  (64KB total)
    const int tid = threadIdx.x;      // 0..511
    const int w = tid >> 6, lane = tid & 63;
    const int c31 = lane & 31, h = lane >> 5;
    const int wm = w >> 2, wn = w & 3;
    // bijective XCD swizzle over 1920 = 8 xcd x 8 panels x 30 col-tiles
    const int id = blockIdx.x;
    const int xcd = id & 7, j = id >> 3;   // j 0..239
    const int by = xcd * 8 + j / 30;
    const int bx = j % 30;
    const bool first = bx < 18;
    const u16* A = first ? A1 : A2;
    const int row0 = by * 128;
    const int nc0 = first ? bx * 128 : 768 + (bx - 18) * 128;

    f32x16 acc[2];
#pragma unroll
    for (int i = 0; i < 2; ++i)
#pragma unroll
        for (int e = 0; e < 16; ++e) acc[i][e] = 0.f;

    // staging: 16KB/matrix = 2 issues x 512 thr x 16B; row = i*64 + tid/8,
    // physical chunk = tid&7, source chunk = (tid&7)^(row&7)
    const int srow = tid >> 3;            // 0..63
    const int sch = ((tid & 7) ^ (srow & 7)) * 8;
    int aoff[2], boff[2];
#pragma unroll
    for (int i = 0; i < 2; ++i) {
        int row = i * 64 + srow;
        aoff[i] = (row0 + row) * C_ + sch;
        boff[i] = (nc0 + row) * C_ + sch;
    }
    char* adst0 = (char*)&As[0][0] + w * 1024;   // wave-uniform base
    char* bdst0 = (char*)&Bs[0][0] + w * 1024;
    auto stage = [&](int buf, int k0) {
#pragma unroll
        for (int i = 0; i < 2; ++i) {
            GLDS16(A + aoff[i] + k0, adst0 + buf * 16384 + i * 8192);
            GLDS16(BT + boff[i] + k0, bdst0 + buf * 16384 + i * 8192);
        }
    };

    // frag rows (row stride 128B; logical chunk 2*kh+h, physical ^(row&7))
    const int ra0 = wm * 64 + c31, ra1 = ra0 + 32;
    const int rb0 = wn * 32 + c31;

    stage(0, 0);
    for (int kt = 0; kt < 12; ++kt) {
        const int buf = kt & 1;
        if (kt < 11) {
            stage(buf ^ 1, (kt + 1) * 64);
            asm volatile("s_waitcnt vmcnt(4)" ::: "memory");
        } else {
            asm volatile("s_waitcnt vmcnt(0)" ::: "memory");
        }
        __builtin_amdgcn_s_barrier();
        const char* abase = (const char*)&As[0][0] + buf * 16384;
        const char* bbase = (const char*)&Bs[0][0] + buf * 16384;
#pragma unroll
        for (int kh = 0; kh < 4; ++kh) {
            bf16x8 a0 = *(const bf16x8*)(abase + ra0 * 128 + (((2 * kh + h) ^ (ra0 & 7)) * 16));
            bf16x8 a1 = *(const bf16x8*)(abase + ra1 * 128 + (((2 * kh + h) ^ (ra1 & 7)) * 16));
            bf16x8 b0 = *(const bf16x8*)(bbase + rb0 * 128 + (((2 * kh + h) ^ (rb0 & 7)) * 16));
            acc[0] = MFMA32(a0, b0, acc[0]);
            acc[1] = MFMA32(a1, b0, acc[1]);
        }
        asm volatile("" ::: "memory");
        __builtin_amdgcn_s_barrier();
    }

    u16* kd  = first ? k1d : k2d;
    u16* vtd = first ? vt1d : vt2d;
    const int col = nc0 + wn * 32 + c31;
    const int sec = col / C_;              // 0=q 1=k 2=v (uniform per wave)
    const int hh = (col % C_) >> 6;
    const int d = col & 63;
    const float scl = (sec == 0) ? 0.180336877f : 1.0f;  // 0.125*log2(e)
#pragma unroll
    for (int mt = 0; mt < 2; ++mt)
#pragma unroll
        for (int r = 0; r < 16; ++r) {
            int row = row0 + wm * 64 + mt * 32 + (r & 3) + 8 * (r >> 2) + 4 * h;
            int b = row >> 10, n = row & 1023;
            u16 val = f2bu(acc[mt][r] * scl);
            size_t bh = (size_t)(b * H_ + hh);
            if (sec == 0)      qd[(bh * N_ + n) * 64 + d] = val;
            else if (sec == 1) kd[(bh * N_ + n) * 64 + d] = val;
            else {
                int nprm = (n & ~63) | (((n & 15) << 2) | ((n >> 4) & 3));
                vtd[(bh * 64 + d) * N_ + nprm] = val;
            }
        }
}

// ---------------------------------------------------------------------------
// Proj GEMM (both branches, one dispatch): 512-thread blocks, same BK=64
// pipeline, bijective XCD swizzle over 768 = 8 xcd x 16 panels x 6 tiles.
// A bf16 @ BT bf16 + bias -> fp32 out.
// ---------------------------------------------------------------------------
__global__ __launch_bounds__(512) void proj_gemm(
    const u16* __restrict__ A1, const u16* __restrict__ A2,
    const u16* __restrict__ BT, const float* __restrict__ bias,
    float* __restrict__ out)
{
    __shared__ u16 As[2][128 * 64];
    __shared__ u16 Bs[2][128 * 64];
    const int tid = threadIdx.x;
    const int w = tid >> 6, lane = tid & 63;
    const int c31 = lane & 31, h = lane >> 5;
    const int wm = w >> 2, wn = w & 3;
    const int id = blockIdx.x;             // 0..767
    const int xcd = id & 7, j = id >> 3;   // j 0..95
    const int byg = xcd * 16 + j / 6;      // 0..127
    const int sel = byg >> 6;
    const u16* A = sel ? A2 : A1;
    float* op = out + (size_t)sel * 8192 * C_;
    const int row0 = (byg & 63) * 128;
    const int nc0 = (j % 6) * 128;

    f32x16 acc[2];
#pragma unroll
    for (int i = 0; i < 2; ++i)
#pragma unroll
        for (int e = 0; e < 16; ++e) acc[i][e] = 0.f;

    const int srow = tid >> 3;
    const int sch = ((tid & 7) ^ (srow & 7)) * 8;
    int aoff[2], boff[2];
#pragma unroll
    for (int i = 0; i < 2; ++i) {
        int row = i * 64 + srow;
        aoff[i] = (row0 + row) * C_ + sch;
        boff[i] = (nc0 + row) * C_ + sch;
    }
    char* adst0 = (char*)&As[0][0] + w * 1024;
    char* bdst0 = (char*)&Bs[0][0] + w * 1024;
    auto stage = [&](int buf, int k0) {
#pragma unroll
        for (int i = 0; i < 2; ++i) {
            GLDS16(A + aoff[i] + k0, adst0 + buf * 16384 + i * 8192);
            GLDS16(BT + boff[i] + k0, bdst0 + buf * 16384 + i * 8192);
        }
    };

    const int ra0 = wm * 64 + c31, ra1 = ra0 + 32;
    const int rb0 = wn * 32 + c31;

    stage(0, 0);
    for (int kt = 0; kt < 12; ++kt) {
        const int buf = kt & 1;
        if (kt < 11) {
            stage(buf ^ 1, (kt + 1) * 64);
            asm volatile("s_waitcnt vmcnt(4)" ::: "memory");
        } else {
            asm volatile("s_waitcnt vmcnt(0)" ::: "memory");
        }
        __builtin_amdgcn_s_barrier();
        const char* abase = (const char*)&As[0][0] + buf * 16384;
        const char* bbase = (const char*)&Bs[0][0] + buf * 16384;
#pragma unroll
        for (int kh = 0; kh < 4; ++kh) {
            bf16x8 a0 = *(const bf16x8*)(abase + ra0 * 128 + (((2 * kh + h) ^ (ra0 & 7)) * 16));
            bf16x8 a1 = *(const bf16x8*)(abase + ra1 * 128 + (((2 * kh + h) ^ (ra1 & 7)) * 16));
            bf16x8 b0 = *(const bf16x8*)(bbase + rb0 * 128 + (((2 * kh + h) ^ (rb0 & 7)) * 16));
            acc[0] = MFMA32(a0, b0, acc[0]);
            acc[1] = MFMA32(a1, b0, acc[1]);
        }
        asm volatile("" ::: "memory");
        __builtin_amdgcn_s_barrier();
    }

    const int col = nc0 + wn * 32 + c31;
#pragma unroll
    for (int mt = 0; mt < 2; ++mt)
#pragma unroll
        for (int r = 0; r < 16; ++r) {
            int row = row0 + wm * 64 + mt * 32 + (r & 3) + 8 * (r >> 2) + 4 * h;
            op[(size_t)row * C_ + col] = acc[mt][r] + bias[col];
        }
}

// ---------------------------------------------------------------------------
// MFMA flash attention, softmax-lite, both branches in one dispatch.
// Round-10..16 proven kernel, unchanged (~890 TF effective).
// ---------------------------------------------------------------------------
__global__ __launch_bounds__(256) void attn_mfma(
    const u16* __restrict__ Q,
    const u16* __restrict__ K1, const u16* __restrict__ VT1,
    const u16* __restrict__ K2, const u16* __restrict__ VT2,
    u16* __restrict__ O1, u16* __restrict__ O2)
{
    __shared__ u16 Ks[2][64 * 64];  // [key][d], swizzled, 8KB per buf
    __shared__ u16 Vs[2][64 * 64];  // [d][key-permuted], swizzled
    __shared__ u16 Ps[4][32 * 72];  // per-wave P, row stride 144B
    const int tid = threadIdx.x;
    const int w = tid >> 6, lane = tid & 63;
    const int g = lane >> 4, ln = lane & 15;
    // XCD swizzle: xcd = id&7 owns 12 heads x 2 branches x 8 q-blocks
    const int id = blockIdx.x;
    const int xcd = id & 7, j = id >> 3;   // j 0..191
    const int unit = j >> 3;               // 0..23
    const int qb = j & 7;
    const int br = unit >= 12;
    const int bh = xcd * 12 + (br ? unit - 12 : unit);
    const int qw = qb * 128 + w * 32;
    const size_t hb = (size_t)bh * N_ * 64;

    const u16* Kb = (br ? K2 : K1) + hb;
    const u16* Vb = (br ? VT2 : VT1) + hb;
    const u16* Qb = Q + hb;
    u16* O        = br ? O2 : O1;

    bf16x8 qf[2][2];
#pragma unroll
    for (int mt = 0; mt < 2; ++mt)
#pragma unroll
        for (int s = 0; s < 2; ++s)
            qf[mt][s] = *(const bf16x8*)(Qb + (size_t)(qw + mt * 16 + ln) * 64 + s * 32 + g * 8);

    f32x4 o[2][4];
    float lsum[2][4];
#pragma unroll
    for (int mt = 0; mt < 2; ++mt) {
#pragma unroll
        for (int t = 0; t < 4; ++t) o[mt][t] = (f32x4){0.f, 0.f, 0.f, 0.f};
#pragma unroll
        for (int r = 0; r < 4; ++r) lsum[mt][r] = 0.f;
    }

    // K/V tile staging: 8KB each = 2 issues x 256 thr x 16B; rows are 128B
    // (8 slots); dest linear, source chunk = slot ^ (row&7)  [rule #21]
    auto stage = [&](int buf, int key0) {
#pragma unroll
        for (int i = 0; i < 2; ++i) {
            int L = (i * 256 + tid) * 16;
            int row = L >> 7;
            int sw = (((L >> 4) & 7) ^ (row & 7)) * 8;
            GLDS16(Kb + (size_t)(key0 + row) * 64 + sw,
                   (char*)&Ks[buf][0] + i * 4096 + w * 1024);
            GLDS16(Vb + (size_t)row * N_ + key0 + sw,
                   (char*)&Vs[buf][0] + i * 4096 + w * 1024);
        }
    };

    u16* pw = &Ps[w][0];
    const int r7 = ln & 7;

    stage(0, 0);
    __syncthreads();
    for (int kt = 0; kt < 16; ++kt) {
        const int buf = kt & 1;
        if (kt < 15) stage(buf ^ 1, (kt + 1) * 64);
        // S = Q K^T  (0.125*log2e pre-folded into Q); K frags from LDS
        const char* kbase = (const char*)&Ks[buf][0];
        f32x4 st[2][4];
#pragma unroll
        for (int nt = 0; nt < 4; ++nt) {
            const char* krow = kbase + (nt * 16 + ln) * 128;
            bf16x8 kf0 = *(const bf16x8*)(krow + ((g ^ r7) * 16));
            bf16x8 kf1 = *(const bf16x8*)(krow + (((g + 4) ^ r7) * 16));
#pragma unroll
            for (int mt = 0; mt < 2; ++mt) {
                f32x4 z = (f32x4){0.f, 0.f, 0.f, 0.f};
                z = MFMA16(qf[mt][0], kf0, z);
                z = MFMA16(qf[mt][1], kf1, z);
                st[mt][nt] = z;
            }
        }
        // softmax-lite: p = exp2(s); lane-local l partials; P pairs -> LDS
#pragma unroll
        for (int mt = 0; mt < 2; ++mt)
#pragma unroll
            for (int r = 0; r < 4; ++r) {
                float p0 = __builtin_amdgcn_exp2f(st[mt][0][r]);
                float p1 = __builtin_amdgcn_exp2f(st[mt][1][r]);
                float p2 = __builtin_amdgcn_exp2f(st[mt][2][r]);
                float p3 = __builtin_amdgcn_exp2f(st[mt][3][r]);
                lsum[mt][r] += (p0 + p1) + (p2 + p3);
                uint2 pk;
                pk.x = cvtpk(p0, p1);
                pk.y = cvtpk(p2, p3);
                int prow = mt * 16 + g * 4 + r;
                *(uint2*)((char*)pw + prow * 144 + ln * 8) = pk;
            }
        // O += P @ V  (A-frag = P from LDS, B-frag = V from LDS, swizzled)
        const char* vbase = (const char*)&Vs[buf][0];
#pragma unroll
        for (int s = 0; s < 2; ++s) {
            bf16x8 pa[2];
            pa[0] = *(const bf16x8*)((const char*)pw + (0 + ln) * 144 + s * 64 + g * 16);
            pa[1] = *(const bf16x8*)((const char*)pw + (16 + ln) * 144 + s * 64 + g * 16);
#pragma unroll
            for (int t = 0; t < 4; ++t) {
                bf16x8 vf = *(const bf16x8*)(vbase + (t * 16 + ln) * 128 + (((s * 4 + g) ^ r7) * 16));
#pragma unroll
                for (int mt = 0; mt < 2; ++mt) o[mt][t] = MFMA16(pa[mt], vf, o[mt][t]);
            }
        }
        __syncthreads();
    }
    // deferred l reduce + epilogue -> O_pre [B][N][C] bf16
    const int b = bh / H_, h = bh % H_;
#pragma unroll
    for (int mt = 0; mt < 2; ++mt)
#pragma unroll
        for (int r = 0; r < 4; ++r) {
            float ls = lsum[mt][r];
#pragma unroll
            for (int off = 8; off; off >>= 1) ls += __shfl_xor(ls, off);
            float inv = 1.f / ls;
            int n = qw + mt * 16 + g * 4 + r;
            u16* orow = O + ((size_t)(b * N_) + n) * C_ + h * 64 + ln;
#pragma unroll
            for (int t = 0; t < 4; ++t)
                orow[t * 16] = f2bu(o[mt][t][r] * inv);
        }
}

extern "C" void kernel_launch(void* const* d_in, const int* in_sizes, int n_in,
                              void* d_out, int out_size, void* d_ws, size_t ws_size,
                              hipStream_t stream) {
    const float* x1     = (const float*)d_in[0];
    const float* x2     = (const float*)d_in[1];
    const float* qkv_w  = (const float*)d_in[2];
    const float* proj_w = (const float*)d_in[3];
    const float* proj_b = (const float*)d_in[4];
    float* out = (float*)d_out;

    // ws layout (u16), 80.2 MB (proven). Alias plan (merge-safe):
    //   x1c/x2c in slotA/slotB are qkv INPUTS only (outputs never alias them);
    //   k2 lives in d_out's out2 region. After qkv both slots are dead ->
    //   attn writes o1p=slotB, o2p=slotA. proj (merged) reads o1p/o2p (ws),
    //   writes out: out2 clobbers dead k2buf; out1 clobbers nothing live.
    u16* ws = (u16*)d_ws;
    const size_t SZ = (size_t)8 * H_ * N_ * 64;  // 6291456 (= 8192*768)
    u16* wqkvT  = ws;
    u16* wprojT = wqkvT + (size_t)2304 * 768;
    u16* q      = wprojT + (size_t)768 * 768;
    u16* k1     = q + SZ;
    u16* vT1    = k1 + SZ;
    u16* slotA  = vT1 + SZ;   // x1c during qkv; o2p afterwards
    u16* vT2    = slotA + SZ;
    u16* slotB  = vT2 + SZ;   // x2c during qkv; o1p afterwards
    u16* x1c = slotA, *o2p = slotA;
    u16* x2c = slotB, *o1p = slotB;
    u16* k2buf = (u16*)(out + SZ);   // scratch inside out-branch-2 region

    cvt_x<<<2048, 256, 0, stream>>>(x1, x2, x1c, x2c);
    tr_cvt<<<dim3(72, 24), 256, 0, stream>>>(qkv_w, wqkvT, C_, 3 * C_);
    tr_cvt<<<dim3(24, 24), 256, 0, stream>>>(proj_w, wprojT, C_, C_);
    qkv_gemm<<<1920, 512, 0, stream>>>(x1c, x2c, wqkvT, q, k1, k2buf, vT1, vT2);
    attn_mfma<<<1536, 256, 0, stream>>>(q, k1, vT1, k2buf, vT2, o1p, o2p);
    proj_gemm<<<768, 512, 0, stream>>>(o1p, o2p, wprojT, proj_b, out);
}